// Round 11
// baseline (202.149 us; speedup 1.0000x reference)
//
#include <hip/hip_runtime.h>
#include <hip/hip_bf16.h>
#include <stdint.h>

// GPT causal self-attention block. B=8, T=1024, C=768, H=8, D=96. f32 I/O.
// bf16 MFMA pipeline with fp32 accumulation. Causal mask input ignored.
//
// R10: store-side epilogue optimization (the R9 lesson generalized).
// (a) qkv Q/K blocks: accumulators transposed through the free 8KB staging
//     arrays (one 64x64 wave-slice each, XOR-swizzled) -> 8 coalesced
//     dwordx4 stores per lane instead of 64 scalar u16 (32B segments).
// (b) attn y-epilogue: same transpose through the free Ks0 wave slice ->
//     3 coalesced 16B stores per lane instead of 24 scalar u16.
// (c) proj retiled 64x128 (grid 128x6 = 768 blocks = 3/CU, no 1.5-gen
//     tail), staging 3 gloads/step with counted vmcnt(3).
// K-loop structures unchanged from R9 (proven).

typedef unsigned short ushort_t;
typedef __attribute__((ext_vector_type(8))) short short8;     // 8 bf16 = 4 VGPRs
typedef __attribute__((ext_vector_type(4))) float floatx4;    // MFMA C/D frag
typedef __attribute__((ext_vector_type(4))) unsigned short ushort4v;

#define MFMA16(a, b, c) __builtin_amdgcn_mfma_f32_16x16x32_bf16(a, b, c, 0, 0, 0)
#define NEG_BIG (-1e30f)

__device__ __forceinline__ unsigned short f2bf(float f) {
  union { float f; unsigned int u; } v; v.f = f;
  unsigned int r = (v.u + 0x7FFFu + ((v.u >> 16) & 1u)) >> 16;  // RNE
  return (unsigned short)r;
}

__device__ __forceinline__ unsigned int packbf2(float a, float b) {
  // low 16 = bf16(a), high 16 = bf16(b)  (v_cvt_pk_bf16_f32)
  union { __hip_bfloat162 h; unsigned int u; } cv;
  cv.h = __float22bfloat162_rn(make_float2(a, b));
  return cv.u;
}

#define GLOAD16(src, dst)                                              \
  __builtin_amdgcn_global_load_lds(                                    \
      (const __attribute__((address_space(1))) void*)(src),            \
      (__attribute__((address_space(3))) void*)(dst), 16, 0, 0)

// counted wait + raw barrier (no vmcnt(0) auto-drain like __syncthreads)
#define WAITBAR_LGKM(VM)                                               \
  do {                                                                 \
    asm volatile("s_waitcnt vmcnt(" #VM ") lgkmcnt(0)" ::: "memory");  \
    __builtin_amdgcn_s_barrier();                                      \
  } while (0)

// ---------------------------------------------------------------------------
// Fused f32->bf16 conversion for x, Wqkv, Wproj in one launch.
// ---------------------------------------------------------------------------
__global__ __launch_bounds__(256) void cvt3(
    const float* __restrict__ x, const float* __restrict__ wa,
    const float* __restrict__ wp, ushort_t* __restrict__ xb,
    ushort_t* __restrict__ wab, ushort_t* __restrict__ wpb)
{
  const int n1 = (8192 * 768) / 4, n2 = (2304 * 768) / 4;
  int i = blockIdx.x * 256 + threadIdx.x;
  const float* in; ushort_t* out;
  if (i < n1)            { in = x;  out = xb; }
  else if (i < n1 + n2)  { in = wa; out = wab; i -= n1; }
  else                   { in = wp; out = wpb; i -= (n1 + n2); }
  float4 v = *(const float4*)(in + (size_t)i * 4);
  ushort4v o;
  o.x = f2bf(v.x); o.y = f2bf(v.y); o.z = f2bf(v.z); o.w = f2bf(v.w);
  *(ushort4v*)(out + (size_t)i * 4) = o;
}

// ---------------------------------------------------------------------------
// qkv GEMM machinery (R7/R9): 128x128 tile, BK=32, 4 waves 2x2, 2 LDS
// buffers, counted vmcnt(4). K = 768 (24 steps), static buffer chain.
// ---------------------------------------------------------------------------
#define GSTAGE(LA, LB, OFF)                                            \
  do {                                                                 \
    GLOAD16(gA + (OFF), &LA[wid * 512]);                               \
    GLOAD16(gA + (OFF) + (size_t)64 * 768, &LA[wid * 512 + 64 * 32]);  \
    GLOAD16(gB + (OFF), &LB[wid * 512]);                               \
    GLOAD16(gB + (OFF) + (size_t)64 * 768, &LB[wid * 512 + 64 * 32]);  \
  } while (0)

#define GSTEP(LA, LB, OFF, STG, VM)                                    \
  do {                                                                 \
    asm volatile("s_waitcnt vmcnt(" #VM ")" ::: "memory");             \
    __builtin_amdgcn_s_barrier();                                      \
    short8 af[4], bf[4];                                               \
    _Pragma("unroll")                                                  \
    for (int t_ = 0; t_ < 4; ++t_) {                                   \
      af[t_] = *(const short8*)&LA[(wm + t_ * 16 + l15) * 32 + sw];    \
      bf[t_] = *(const short8*)&LB[(wn + t_ * 16 + l15) * 32 + sw];    \
    }                                                                  \
    asm volatile("s_waitcnt lgkmcnt(0)" ::: "memory");                 \
    __builtin_amdgcn_s_barrier();                                      \
    if (STG) GSTAGE(LA, LB, OFF);                                      \
    __builtin_amdgcn_s_setprio(1);                                     \
    _Pragma("unroll")                                                  \
    for (int tm = 0; tm < 4; ++tm)                                     \
      _Pragma("unroll")                                                \
      for (int tn = 0; tn < 4; ++tn)                                   \
        acc[tm][tn] = MFMA16(af[tm], bf[tn], acc[tm][tn]);             \
    __builtin_amdgcn_s_setprio(0);                                     \
  } while (0)

#define GK2(T)                                                         \
  GSTEP(As0, Bs0, ((T) + 2) * 32, 1, 4);                               \
  GSTEP(As1, Bs1, ((T) + 3) * 32, 1, 4);

#define GEMM_KLOOP                                                     \
  GSTAGE(As0, Bs0, 0); GSTAGE(As1, Bs1, 32);                           \
  GK2(0) GK2(2) GK2(4) GK2(6) GK2(8) GK2(10)                           \
  GK2(12) GK2(14) GK2(16) GK2(18) GK2(20)                              \
  GSTEP(As0, Bs0, 0, 0, 4);                                            \
  GSTEP(As1, Bs1, 0, 0, 0);

// ---------------------------------------------------------------------------
// QKV GEMM. Q pre-scaled by (1/sqrt(96))*log2e. Q/K epilogue: LDS-transposed
// coalesced stores (each wave's 64x64 bf16 sub-tile = exactly one free 8KB
// staging array, XOR-swizzled rows). V epilogue: packed 8B VT stores (R9).
// ---------------------------------------------------------------------------
__global__ __launch_bounds__(256) void gemm_qkv(
    const ushort_t* __restrict__ A,   // 8192 x 768 bf16 (x)
    const ushort_t* __restrict__ W,   // 2304 x 768 bf16
    const float* __restrict__ bias,   // 2304 f32
    ushort_t* __restrict__ QK,        // 8192 x 1536 bf16
    ushort_t* __restrict__ VT)        // (64 bh) x 96 x 1024 bf16 (perm cols)
{
  __shared__ ushort_t As0[128 * 32], As1[128 * 32];
  __shared__ ushort_t Bs0[128 * 32], Bs1[128 * 32];
  const int tid  = threadIdx.x;
  const int lane = tid & 63;
  const int l15  = lane & 15;
  const int quad = lane >> 4;
  const int wid  = tid >> 6;
  const int m0 = blockIdx.x * 128;
  const int n0 = blockIdx.y * 128;
  const int wm = (wid >> 1) * 64;
  const int wn = (wid & 1) * 64;
  const int srow = tid >> 2;
  const int scol = (((tid & 3) ^ ((srow ^ (srow >> 2)) & 3))) * 8;
  const int sw = (quad ^ ((l15 ^ (l15 >> 2)) & 3)) * 8;
  floatx4 acc[4][4] = {};

  const ushort_t* gA = A + (size_t)(m0 + srow) * 768 + scol;
  const ushort_t* gB = W + (size_t)(n0 + srow) * 768 + scol;

  GEMM_KLOOP;

  // all waves' LDS reads retired before staging arrays are reused
  asm volatile("s_waitcnt lgkmcnt(0)" ::: "memory");
  __builtin_amdgcn_s_barrier();

  const float QSCALE = 0.10206207261596577f * 1.4426950408889634f;

  if (n0 < 1536) {
    // -------- Q/K path: LDS transpose -> coalesced 16B stores --------
    ushort_t* tb = (wid == 0) ? As0 : (wid == 1) ? As1
                 : (wid == 2) ? Bs0 : Bs1;            // wave's 8KB slice
    const float qs = (n0 < 768) ? QSCALE : 1.0f;      // block-uniform
#pragma unroll
    for (int tn = 0; tn < 4; ++tn) {
      const float bv = bias[n0 + wn + tn * 16 + l15];
#pragma unroll
      for (int tm = 0; tm < 4; ++tm)
#pragma unroll
        for (int r = 0; r < 4; ++r) {
          const int row = tm * 16 + quad * 4 + r;     // 0..63
          const int byte = (row * 128 + (tn * 16 + l15) * 2) ^
                           ((row & 7) << 4);          // XOR bank swizzle
          *(ushort_t*)((char*)tb + byte) = f2bf((acc[tm][tn][r] + bv) * qs);
        }
    }
    asm volatile("s_waitcnt lgkmcnt(0)" ::: "memory");  // in-wave w->r
    const int trow = lane >> 2, ts = lane & 3;
#pragma unroll
    for (int p = 0; p < 4; ++p) {
      const int row = trow + p * 16;
      const int swz = (row & 7) << 4;
#pragma unroll
      for (int k = 0; k < 2; ++k) {
        const int byte = (row * 128 + ts * 32 + k * 16) ^ swz;
        short8 v = *(const short8*)((char*)tb + byte);
        *(short8*)(QK + (size_t)(m0 + wm + row) * 1536 +
                   n0 + wn + ts * 16 + k * 8) = v;
      }
    }
  } else {
    // -------- V path: sigma-permuted VT, packed 8B stores (R9) --------
#pragma unroll
    for (int tn = 0; tn < 4; ++tn) {
      const int gc = n0 + wn + tn * 16 + l15;
      const float bv = bias[gc];
      const int hh = (gc - 1536) / 96, dd = (gc - 1536) % 96;
#pragma unroll
      for (int tm = 0; tm < 4; ++tm) {
        const int gr = m0 + wm + tm * 16 + quad * 4;   // multiple of 4
        const int bb = gr >> 10, tt = gr & 1023;       // same bb for r=0..3
        const int tt2 = (tt & ~0x1C) | (((tt >> 4) & 1) << 2) |
                        (((tt >> 2) & 3) << 3);        // bits 0-1 preserved
        ushort4v o;
        o.x = f2bf(acc[tm][tn][0] + bv);
        o.y = f2bf(acc[tm][tn][1] + bv);
        o.z = f2bf(acc[tm][tn][2] + bv);
        o.w = f2bf(acc[tm][tn][3] + bv);
        *(ushort4v*)(VT + (((size_t)(bb * 8 + hh)) * 96 + dd) * 1024 + tt2) = o;
      }
    }
  }
}

// ---------------------------------------------------------------------------
// proj GEMM: 64x128 tile (grid 128x6 = 768 blocks = 3/CU, no 1.5-gen tail).
// BK=32, 4 waves 2x2 (32x64 each), 2 LDS buffers, counted vmcnt(3)
// (3 gloads per stage). f32 output stores are already full-line (64B).
// ---------------------------------------------------------------------------
#define PSTAGE(LA, LB, OFF)                                            \
  do {                                                                 \
    GLOAD16(gA + (OFF), &LA[wid * 512]);                               \
    GLOAD16(gB + (OFF), &LB[wid * 512]);                               \
    GLOAD16(gB + (OFF) + (size_t)64 * 768, &LB[wid * 512 + 64 * 32]);  \
  } while (0)

#define PSTEP(LA, LB, OFF, STG, VM)                                    \
  do {                                                                 \
    asm volatile("s_waitcnt vmcnt(" #VM ")" ::: "memory");             \
    __builtin_amdgcn_s_barrier();                                      \
    short8 af[2], bf[4];                                               \
    _Pragma("unroll")                                                  \
    for (int t_ = 0; t_ < 2; ++t_)                                     \
      af[t_] = *(const short8*)&LA[(wm + t_ * 16 + l15) * 32 + sw];    \
    _Pragma("unroll")                                                  \
    for (int t_ = 0; t_ < 4; ++t_)                                     \
      bf[t_] = *(const short8*)&LB[(wn + t_ * 16 + l15) * 32 + sw];    \
    asm volatile("s_waitcnt lgkmcnt(0)" ::: "memory");                 \
    __builtin_amdgcn_s_barrier();                                      \
    if (STG) PSTAGE(LA, LB, OFF);                                      \
    __builtin_amdgcn_s_setprio(1);                                     \
    _Pragma("unroll")                                                  \
    for (int tm = 0; tm < 2; ++tm)                                     \
      _Pragma("unroll")                                                \
      for (int tn = 0; tn < 4; ++tn)                                   \
        acc[tm][tn] = MFMA16(af[tm], bf[tn], acc[tm][tn]);             \
    __builtin_amdgcn_s_setprio(0);                                     \
  } while (0)

#define PK2(T)                                                         \
  PSTEP(As0, Bs0, ((T) + 2) * 32, 1, 3);                               \
  PSTEP(As1, Bs1, ((T) + 3) * 32, 1, 3);

__global__ __launch_bounds__(256) void gemm_proj(
    const ushort_t* __restrict__ A,   // M x 768 bf16
    const ushort_t* __restrict__ W,   // N x 768 bf16
    const float* __restrict__ bias,   // N f32
    float* __restrict__ C,            // M x N f32
    int M, int N)
{
  __shared__ ushort_t As0[64 * 32], As1[64 * 32];
  __shared__ ushort_t Bs0[128 * 32], Bs1[128 * 32];
  const int tid  = threadIdx.x;
  const int lane = tid & 63;
  const int l15  = lane & 15;
  const int quad = lane >> 4;
  const int wid  = tid >> 6;
  const int m0 = blockIdx.x * 64;
  const int n0 = blockIdx.y * 128;
  const int wm = (wid >> 1) * 32;
  const int wn = (wid & 1) * 64;
  const int srow = tid >> 2;
  const int scol = (((tid & 3) ^ ((srow ^ (srow >> 2)) & 3))) * 8;
  const int sw = (quad ^ ((l15 ^ (l15 >> 2)) & 3)) * 8;
  floatx4 acc[2][4] = {};

  const ushort_t* gA = A + (size_t)(m0 + srow) * 768 + scol;
  const ushort_t* gB = W + (size_t)(n0 + srow) * 768 + scol;

  PSTAGE(As0, Bs0, 0); PSTAGE(As1, Bs1, 32);
  PK2(0) PK2(2) PK2(4) PK2(6) PK2(8) PK2(10)
  PK2(12) PK2(14) PK2(16) PK2(18) PK2(20)
  PSTEP(As0, Bs0, 0, 0, 3);
  PSTEP(As1, Bs1, 0, 0, 0);

#pragma unroll
  for (int tn = 0; tn < 4; ++tn) {
    const int gc = n0 + wn + tn * 16 + l15;
    const float bv = bias[gc];
#pragma unroll
    for (int tm = 0; tm < 2; ++tm) {
      const int gr = m0 + wm + tm * 16 + quad * 4;
#pragma unroll
      for (int r = 0; r < 4; ++r)
        C[(size_t)(gr + r) * N + gc] = acc[tm][tn][r] + bv;
    }
  }
}

// ---------------------------------------------------------------------------
// Fused causal flash attention (R9 structure + LDS-transposed y epilogue).
// Grid (16, 64); block = one 64-row q-chunk of one (b,h); XCD swizzle + LPT.
// ---------------------------------------------------------------------------
#define ATTN_COMPUTE(KS, VTC, K0)                                      \
  do {                                                                 \
    floatx4 s[4] = {};                                                 \
    __builtin_amdgcn_s_setprio(1);                                     \
    _Pragma("unroll")                                                  \
    for (int t = 0; t < 4; ++t) {                                      \
      _Pragma("unroll")                                                \
      for (int c = 0; c < 3; ++c) {                                    \
        short8 kf = *(const short8*)                                   \
            &KS[(t * 16 + l15) * 96 + c * 32 + quad * 8];              \
        s[t] = MFMA16(kf, qf[c], s[t]);                                \
      }                                                                \
    }                                                                  \
    __builtin_amdgcn_s_setprio(0);                                     \
    float p[4][4];                                                     \
    if ((K0) + 64 <= q0w) {                                            \
      _Pragma("unroll")                                                \
      for (int t = 0; t < 4; ++t)                                      \
        _Pragma("unroll")                                              \
        for (int j = 0; j < 4; ++j) p[t][j] = s[t][j];                 \
    } else {                                                           \
      const int kq = (K0) + quad * 4;                                  \
      _Pragma("unroll")                                                \
      for (int t = 0; t < 4; ++t)                                      \
        _Pragma("unroll")                                              \
        for (int j = 0; j < 4; ++j)                                    \
          p[t][j] = (kq + t * 16 + j <= rq) ? s[t][j] : NEG_BIG;       \
    }                                                                  \
    float m0v = fmaxf(fmaxf(p[0][0], p[0][1]), fmaxf(p[0][2], p[0][3]));\
    float m1v = fmaxf(fmaxf(p[1][0], p[1][1]), fmaxf(p[1][2], p[1][3]));\
    float m2v = fmaxf(fmaxf(p[2][0], p[2][1]), fmaxf(p[2][2], p[2][3]));\
    float m3v = fmaxf(fmaxf(p[3][0], p[3][1]), fmaxf(p[3][2], p[3][3]));\
    float mt = fmaxf(fmaxf(m0v, m1v), fmaxf(m2v, m3v));                \
    mt = fmaxf(mt, __shfl_xor(mt, 16));                                \
    mt = fmaxf(mt, __shfl_xor(mt, 32));                                \
    if (!__all(mt - m_i <= 8.0f)) {                                    \
      const float mn = fmaxf(m_i, mt);                                 \
      const float al = __builtin_amdgcn_exp2f(m_i - mn);               \
      m_i = mn;                                                        \
      l_i *= al;                                                       \
      _Pragma("unroll")                                                \
      for (int j = 0; j < 4; ++j) {                                    \
        const float alr = __shfl(al, quad * 4 + j);                    \
        _Pragma("unroll")                                              \
        for (int f = 0; f < 6; ++f) O[f][j] *= alr;                    \
      }                                                                \
    }                                                                  \
    float rs = 0.f;                                                    \
    _Pragma("unroll")                                                  \
    for (int t = 0; t < 4; ++t)                                        \
      _Pragma("unroll")                                                \
      for (int j = 0; j < 4; ++j) {                                    \
        p[t][j] = __builtin_amdgcn_exp2f(p[t][j] - m_i);               \
        rs += p[t][j];                                                 \
      }                                                                \
    rs += __shfl_xor(rs, 16);                                          \
    rs += __shfl_xor(rs, 32);                                          \
    l_i += rs;                                                         \
    union { short8 s8; unsigned int u[4]; } pf0, pf1;                  \
    pf0.u[0] = packbf2(p[0][0], p[0][1]);                              \
    pf0.u[1] = packbf2(p[0][2], p[0][3]);                              \
    pf0.u[2] = packbf2(p[1][0], p[1][1]);                              \
    pf0.u[3] = packbf2(p[1][2], p[1][3]);                              \
    pf1.u[0] = packbf2(p[2][0], p[2][1]);                              \
    pf1.u[1] = packbf2(p[2][2], p[2][3]);                              \
    pf1.u[2] = packbf2(p[3][0], p[3][1]);                              \
    pf1.u[3] = packbf2(p[3][2], p[3][3]);                              \
    __builtin_amdgcn_s_setprio(1);                                     \
    _Pragma("unroll")                                                  \
    for (int f = 0; f < 6; ++f) {                                      \
      short8 vf0 = *(const short8*)&VTC[(f * 16 + l15) * 72 + quad * 8];\
      O[f] = MFMA16(pf0.s8, vf0, O[f]);                                \
      short8 vf1 = *(const short8*)                                    \
          &VTC[(f * 16 + l15) * 72 + 32 + quad * 8];                   \
      O[f] = MFMA16(pf1.s8, vf1, O[f]);                                \
    }                                                                  \
    __builtin_amdgcn_s_setprio(0);                                     \
  } while (0)

#define AITER(KS, VTC, KSN, VTN, K0)                                   \
  do {                                                                 \
    const int k0_ = (K0);                                              \
    const int nk_ = k0_ + 64;                                          \
    WAITBAR_LGKM(3);                                                   \
    _Pragma("unroll")                                                  \
    for (int i = 0; i < 3; ++i) {                                      \
      const int e = ke0 + i * 512;                                     \
      const int kr = e / 96, kc = e % 96;                              \
      GLOAD16(QK + (rowbase + nk_ + kr) * 1536 + 768 + qoff + kc,      \
              &KSN[wid * 1536 + i * 512]);                             \
    }                                                                  \
    ATTN_COMPUTE(KS, VTC, k0_);                                        \
    _Pragma("unroll")                                                  \
    for (int g = 0; g < 3; ++g)                                        \
      *(short8*)&VTN[(g * 32 + vd) * 72 + vkc] = vreg[g];              \
    if (nk_ + 64 < kend) {                                             \
      _Pragma("unroll")                                                \
      for (int g = 0; g < 3; ++g)                                      \
        vreg[g] = *(const short8*)                                     \
            (vtb + (size_t)(g * 32 + vd) * 1024 + nk_ + 64 + vkc);     \
    }                                                                  \
  } while (0)

#define AITER_LAST(KS, VTC, K0)                                        \
  do {                                                                 \
    WAITBAR_LGKM(0);                                                   \
    ATTN_COMPUTE(KS, VTC, (K0));                                       \
  } while (0)

__global__ __launch_bounds__(256) void attn_fused(
    const ushort_t* __restrict__ QK,   // (B*T) x 1536 bf16  [q*scale | k]
    const ushort_t* __restrict__ VT,   // (64 bh) x 96 x 1024 bf16 (perm cols)
    ushort_t* __restrict__ y)          // (B*T) x 768 bf16
{
  __shared__ ushort_t Ks0[64 * 96], Ks1[64 * 96];
  __shared__ ushort_t Vt0[96 * 72], Vt1[96 * 72];

  const int tid  = threadIdx.x;
  const int lane = tid & 63;
  const int l15  = lane & 15;
  const int quad = lane >> 4;
  const int wid  = tid >> 6;

  // XCD-swizzled work assignment + LPT: heavy chunks dispatch first.
  const int lin = blockIdx.x + (blockIdx.y << 4);
  const int swz = ((lin & 7) << 7) + (lin >> 3);
  const int chunk = 15 - (swz & 15);   // 15..0 (heavy first)
  const int bh = swz >> 4;             // 0..63
  const int b = bh >> 3;
  const int h = bh & 7;
  const int qoff = h * 96;

  const int q0w = chunk * 64 + wid * 16;   // wave's first q row
  const int kend = chunk * 64 + 64;        // block loop bound == causal bound
  const int rq = q0w + l15;                // this lane's q row

  const size_t rowbase = (size_t)b * 1024;
  const ushort_t* vtb = VT + (size_t)bh * 96 * 1024;

  // per-thread staging coords
  const int ke0 = wid * 1536 + lane * 8;           // K-stage element base
  const int vd  = (tid >> 3);                      // V-stage row within group
  const int vkc = (tid & 7) * 8;                   // V-stage col

  // Q fragments (used as B operand), K=96 in 3 chunks of 32
  short8 qf[3];
#pragma unroll
  for (int c = 0; c < 3; ++c)
    qf[c] = *(const short8*)(QK + (rowbase + q0w + l15) * 1536 + qoff +
                             c * 32 + quad * 8);

  float m_i = NEG_BIG;   // running max for row l15 (exp2 domain)
  float l_i = 0.f;       // running denom for row l15
  floatx4 O[6] = {};

  short8 vreg[3];

  // prologue: V(0) regs FIRST, K(0) gloads, write V(0), issue V(1) regs.
#pragma unroll
  for (int g = 0; g < 3; ++g)
    vreg[g] = *(const short8*)(vtb + (size_t)(g * 32 + vd) * 1024 + vkc);
#pragma unroll
  for (int i = 0; i < 3; ++i) {
    const int e = ke0 + i * 512;
    const int kr = e / 96, kc = e % 96;
    GLOAD16(QK + (rowbase + kr) * 1536 + 768 + qoff + kc,
            &Ks0[wid * 1536 + i * 512]);
  }
#pragma unroll
  for (int g = 0; g < 3; ++g)
    *(short8*)&Vt0[(g * 32 + vd) * 72 + vkc] = vreg[g];
#pragma unroll
  for (int g = 0; g < 3; ++g)
    vreg[g] = *(const short8*)(vtb + (size_t)(g * 32 + vd) * 1024 + 64 + vkc);

  // main loop: pairs of tiles with static buffers; 1-or-2 iteration tail.
  int k0 = 0;
  while (k0 + 128 < kend) {
    AITER(Ks0, Vt0, Ks1, Vt1, k0);
    AITER(Ks1, Vt1, Ks0, Vt0, k0 + 64);
    k0 += 128;
  }
  if (k0 + 64 < kend) {
    AITER(Ks0, Vt0, Ks1, Vt1, k0);
    AITER_LAST(Ks1, Vt1, k0 + 64);
  } else {
    AITER_LAST(Ks0, Vt0, k0);
  }

  // ---- epilogue: transpose O through free Ks0 slice -> coalesced stores ----
  asm volatile("s_waitcnt vmcnt(0) lgkmcnt(0)" ::: "memory");
  __builtin_amdgcn_s_barrier();   // all waves done reading Ks0/Vt* tiles

  float inv[4];
#pragma unroll
  for (int j = 0; j < 4; ++j) {
    const float lj = __shfl(l_i, quad * 4 + j);
    inv[j] = 1.0f / fmaxf(lj, 1e-20f);
  }
  ushort_t* tb = &Ks0[wid * 1536];   // wave's 16 rows x 96 cols slice
#pragma unroll
  for (int j = 0; j < 4; ++j)
#pragma unroll
    for (int f = 0; f < 6; ++f)
      tb[(quad * 4 + j) * 96 + f * 16 + l15] = f2bf(O[f][j] * inv[j]);
  asm volatile("s_waitcnt lgkmcnt(0)" ::: "memory");  // in-wave w->r

  const int trow = lane >> 2, ts = lane & 3;
  const size_t grow = rowbase + q0w + trow;
#pragma unroll
  for (int k = 0; k < 3; ++k) {
    short8 v = *(const short8*)&tb[trow * 96 + ts * 24 + k * 8];
    *(short8*)(y + grow * 768 + qoff + ts * 24 + k * 8) = v;
  }
}

// ---------------------------------------------------------------------------
extern "C" void kernel_launch(void* const* d_in, const int* in_sizes, int n_in,
                              void* d_out, int out_size, void* d_ws, size_t ws_size,
                              hipStream_t stream)
{
  const float* x_f  = (const float*)d_in[0];
  const float* wa_f = (const float*)d_in[1];
  const float* ba_f = (const float*)d_in[2];
  const float* wp_f = (const float*)d_in[3];
  const float* bp_f = (const float*)d_in[4];
  float* out = (float*)d_out;

  ushort_t* xb  = (ushort_t*)d_ws;                    // 8192 x  768
  ushort_t* wab = xb  + (size_t)8192 * 768;           // 2304 x  768
  ushort_t* wpb = wab + (size_t)2304 * 768;           //  768 x  768
  ushort_t* QK  = wpb + (size_t)768 * 768;            // 8192 x 1536
  ushort_t* VT  = QK  + (size_t)8192 * 1536;          // 64 x 96 x 1024
  ushort_t* yw  = VT  + (size_t)8192 * 768;           // 8192 x  768

  // (8192*768 + 2304*768 + 768*768)/4 = 2162688 = 8448 * 256
  cvt3<<<8448, 256, 0, stream>>>(x_f, wa_f, wp_f, xb, wab, wpb);

  gemm_qkv<<<dim3(64, 18), 256, 0, stream>>>(xb, wab, ba_f, QK, VT);
  attn_fused<<<dim3(16, 64), 256, 0, stream>>>(QK, VT, yw);
  gemm_proj<<<dim3(128, 6), 256, 0, stream>>>(yw, wpb, bp_f, out,
                                              8192, 768);
}